// Round 9
// baseline (508.516 us; speedup 1.0000x reference)
//
#include <hip/hip_runtime.h>
#include <cstdint>

typedef unsigned short u16;
typedef float  f32x4  __attribute__((ext_vector_type(4)));
typedef float  f32x16 __attribute__((ext_vector_type(16)));
typedef short  s16x8  __attribute__((ext_vector_type(8)));

#define D_IN  4096
#define D_OUT 4096
#define RMOE  128
#define KAUG  4224   /* D_IN + RMOE */
#define NTOK  8192   /* B*S = 4*2048 */

__device__ __forceinline__ u16 f2bf(float f) {
    unsigned u = __builtin_bit_cast(unsigned, f);
    unsigned r = u + 0x7fffu + ((u >> 16) & 1u);   // RNE
    return (u16)(r >> 16);
}

__device__ __forceinline__ void gload16(const void* g, void* l) {
    __builtin_amdgcn_global_load_lds(
        (const __attribute__((address_space(1))) void*)g,
        (__attribute__((address_space(3))) void*)l, 16, 0, 0);
}

// ---------------------------------------------------------------------------
// Kernel 1: fp32 -> bf16 conversions into augmented layouts. (unchanged)
// ---------------------------------------------------------------------------
__global__ __launch_bounds__(256)
void convert_kernel(const float* __restrict__ x, const float* __restrict__ bw,
                    const float* __restrict__ lA, const float* __restrict__ lB,
                    u16* __restrict__ Xaug, u16* __restrict__ Waug,
                    u16* __restrict__ A16) {
    const long nx = (long)NTOK * D_IN / 8;    // 4,194,304
    const long nw = (long)D_OUT * D_IN / 8;   // 2,097,152
    const long nb = (long)D_OUT * RMOE / 8;   // 65,536
    long tid = (long)blockIdx.x * 256 + threadIdx.x;
    const float* src; u16* dst;
    if (tid < nx) {
        long e = tid * 8; long row = e >> 12; long col = e & 4095;
        src = x + e; dst = Xaug + row * KAUG + col;
    } else if (tid < nx + nw) {
        long e = (tid - nx) * 8; long row = e >> 12; long col = e & 4095;
        src = bw + e; dst = Waug + row * KAUG + col;
    } else if (tid < nx + nw + nb) {
        long e = (tid - nx - nw) * 8; long row = e >> 7; long col = e & 127;
        src = lB + e; dst = Waug + row * KAUG + D_IN + col;
    } else {
        long e = (tid - nx - nw - nb) * 8;
        src = lA + e; dst = A16 + e;
    }
    float4 a = ((const float4*)src)[0];
    float4 b = ((const float4*)src)[1];
    s16x8 o;
    o[0] = (short)f2bf(a.x); o[1] = (short)f2bf(a.y);
    o[2] = (short)f2bf(a.z); o[3] = (short)f2bf(a.w);
    o[4] = (short)f2bf(b.x); o[5] = (short)f2bf(b.y);
    o[6] = (short)f2bf(b.z); o[7] = (short)f2bf(b.w);
    *(s16x8*)dst = o;
}

// ---------------------------------------------------------------------------
// Kernel 2: router in fp32 — ROUND-9: 8 tokens per wave. rw float4s loaded
// once per k-chunk are reused across the wave's 8 tokens (rw L2 traffic /8).
// Per-lane accumulation order and butterfly IDENTICAL to the validated
// 1-token router (bit-identical numerics); static-unrolled lane==t top-2.
// ---------------------------------------------------------------------------
__global__ __launch_bounds__(256)
void router_kernel(const float* __restrict__ x, const float* __restrict__ rw,
                   const float* __restrict__ scal, float* __restrict__ gates) {
    int wave = threadIdx.x >> 6, lane = threadIdx.x & 63;
    int t0 = blockIdx.x * 32 + wave * 8;          // 8 tokens per wave
    const float4* rwp = (const float4*)rw;        // [8][1024] float4
    float acc[8][8];                              // [token][expert]
#pragma unroll
    for (int t = 0; t < 8; ++t)
#pragma unroll
        for (int e = 0; e < 8; ++e) acc[t][e] = 0.f;

    for (int i = 0; i < 16; ++i) {
        float4 wv[8];
#pragma unroll
        for (int e = 0; e < 8; ++e) wv[e] = rwp[e * 1024 + i * 64 + lane];
#pragma unroll
        for (int t = 0; t < 8; ++t) {
            float4 xv = ((const float4*)(x + (long)(t0 + t) * D_IN))[i * 64 + lane];
#pragma unroll
            for (int e = 0; e < 8; ++e)
                acc[t][e] += xv.x * wv[e].x + xv.y * wv[e].y
                           + xv.z * wv[e].z + xv.w * wv[e].w;
        }
    }
#pragma unroll
    for (int t = 0; t < 8; ++t)
#pragma unroll
        for (int e = 0; e < 8; ++e)
#pragma unroll
            for (int off = 32; off > 0; off >>= 1)
                acc[t][e] += __shfl_xor(acc[t][e], off, 64);

#pragma unroll
    for (int t = 0; t < 8; ++t) {
        if (lane == t) {
            int i1 = 0; float v1 = acc[t][0];
#pragma unroll
            for (int e = 1; e < 8; ++e) if (acc[t][e] > v1) { v1 = acc[t][e]; i1 = e; }
            int i2 = -1; float v2 = -3.4e38f;
#pragma unroll
            for (int e = 0; e < 8; ++e)
                if (e != i1 && acc[t][e] > v2) { v2 = acc[t][e]; i2 = e; }
            float g1 = 1.f / (1.f + expf(v2 - v1));
            float g2 = 1.f - g1;
            float* gp = gates + (long)(t0 + t) * 8;
#pragma unroll
            for (int e = 0; e < 8; ++e)
                gp[e] = (e == i1) ? g1 * scal[e] : ((e == i2) ? g2 * scal[e] : 0.f);
        }
    }
}

// ---------------------------------------------------------------------------
// Kernel 3: h_scaled = (x @ lora_A^T) * gate, bf16 into Xaug cols 4096..4223.
// (unchanged)
// ---------------------------------------------------------------------------
__global__ __launch_bounds__(256)
void lora_h_kernel(u16* __restrict__ Xaug, const u16* __restrict__ A16,
                   const float* __restrict__ gates) {
    __shared__ u16 sX[64 * 32];
    __shared__ u16 sW[64 * 32];
    int tid = threadIdx.x, wave = tid >> 6, lane = tid & 63;
    int bm = blockIdx.x >> 1, bn = blockIdx.x & 1;
    long m0 = (long)bm * 64; int n0 = bn * 64;
    int wr = wave >> 1, wc = wave & 1;
    int c = wave * 64 + lane, row = c >> 2, oct = c & 3;
    const u16* gx = Xaug + (m0 + row) * KAUG + oct * 8;
    const u16* gw = A16 + (long)(n0 + row) * D_IN + oct * 8;
    u16* lx = sX + wave * 512;
    u16* lw = sW + wave * 512;
    int cl = lane & 15, kh = lane >> 4;
    int aoff[2], boff[2];
#pragma unroll
    for (int i = 0; i < 2; ++i) {
        aoff[i] = (wr * 32 + i * 16 + cl) * 32 + kh * 8;
        boff[i] = (wc * 32 + i * 16 + cl) * 32 + kh * 8;
    }
    f32x4 acc[2][2];
#pragma unroll
    for (int i = 0; i < 2; ++i)
#pragma unroll
        for (int j = 0; j < 2; ++j) acc[i][j] = (f32x4){0.f, 0.f, 0.f, 0.f};
    for (int kt = 0; kt < 128; ++kt) {
        __syncthreads();
        gload16(gx, lx); gload16(gw, lw);
        gx += 32; gw += 32;
        __syncthreads();
        s16x8 a[2], b[2];
#pragma unroll
        for (int i = 0; i < 2; ++i) {
            a[i] = *(const s16x8*)&sX[aoff[i]];
            b[i] = *(const s16x8*)&sW[boff[i]];
        }
#pragma unroll
        for (int mi = 0; mi < 2; ++mi)
#pragma unroll
            for (int ni = 0; ni < 2; ++ni)
                acc[mi][ni] = __builtin_amdgcn_mfma_f32_16x16x32_bf16(
                    a[mi], b[ni], acc[mi][ni], 0, 0, 0);
    }
#pragma unroll
    for (int ni = 0; ni < 2; ++ni) {
        int col = n0 + wc * 32 + ni * 16 + cl;
        int g = col >> 4;
#pragma unroll
        for (int mi = 0; mi < 2; ++mi) {
#pragma unroll
            for (int r = 0; r < 4; ++r) {
                long tok = m0 + wr * 32 + mi * 16 + kh * 4 + r;
                float v = acc[mi][ni][r] * gates[tok * 8 + g];
                Xaug[tok * KAUG + D_IN + col] = f2bf(v);
            }
        }
    }
}

// ---------------------------------------------------------------------------
// Kernel 4: main GEMM, 256x256 tile, BK=32, 8 waves (2Mx4N), 4-deep LDS
// pipeline, counted vmcnt (T4) + XCD swizzle (T1) + T2 LDS swizzle.
// Schedule = round-6 2-phase body (best measured: 297 us).
//
// ROUND-9 CHANGE: MFMA shape 16x16x32 -> 32x32x16 (higher measured pipe
// ceiling 2495 vs 2075 TF, half the issue slots; LDS traffic unchanged).
// Per wave: 4m x 2n frags of 32x32, acc f32x16 each (128 f32, same as
// before). A/B frag: row = lane&31, k = (lane>>5)*8 + i. C/D (verified
// m74/m101): col = lane&31, row = (reg&3) + 8*(reg>>2) + 4*(lane>>5).
// Same slot-XOR swizzle: LDS[row][j] = global[row][j ^ ((row>>1)&3)],
// j = 8-el slot; read slot = (kk*2 + (lane>>5)) ^ ((r31>>1)&3).
// ---------------------------------------------------------------------------
__global__ __launch_bounds__(512, 2)
void main_gemm(const u16* __restrict__ Xaug, const u16* __restrict__ Waug,
               const float* __restrict__ bias, float* __restrict__ out) {
    __shared__ u16 lds[4 * 16384];     // 128 KiB
    const int tid = threadIdx.x;
    const int wave = tid >> 6, lane = tid & 63;
    const int r31 = lane & 31, hk = lane >> 5;
    const int wr = wave >> 2, wc = wave & 3;

    // T1: bijective XCD swizzle (512 blocks, 512 % 8 == 0)
    int bid = blockIdx.x;
    int swz = (bid & 7) * 64 + (bid >> 3);
    long m0 = (long)(swz & 31) * 256;   // 32 M-blocks
    long n0 = (long)(swz >> 5) * 256;   // 16 N-blocks

    // staging: thread covers row rA (+128), slot (tid&3); source slot XOR'd
    // by ((row>>1)&3) == ((tid>>3)&3)  (T2, rule #21).
    const int rA = tid >> 2;
    const int sl = (((tid & 3) ^ ((tid >> 3) & 3))) * 8;
    const u16* gA0 = Xaug + (m0 + rA) * KAUG + sl;
    const u16* gA1 = Xaug + (m0 + 128 + rA) * KAUG + sl;
    const u16* gB0 = Waug + (n0 + rA) * KAUG + sl;
    const u16* gB1 = Waug + (n0 + 128 + rA) * KAUG + sl;
    const int wbase = wave * 512;       // wave-uniform LDS base (el)

    // read side: slot for kk = (kk*2 + hk) ^ ((r31>>1)&3), in 8-el units
    const int sx = (r31 >> 1) & 3;
    const int skk0 = ((0 + hk) ^ sx) * 8;        // kk=0
    const int skk1 = ((2 + hk) ^ sx) * 8;        // kk=1
    const int abase = (wr * 128 + r31) * 32;     // + mf*1024 + skk
    const int bbase = 8192 + (wc * 64 + r31) * 32;  // + nf*1024 + skk

    f32x16 acc[4][2];
#pragma unroll
    for (int m = 0; m < 4; ++m)
#pragma unroll
        for (int n = 0; n < 2; ++n)
#pragma unroll
            for (int r = 0; r < 16; ++r) acc[m][n][r] = 0.f;

#define STAGE_A(t) do { u16* L = lds + ((t) & 3) * 16384 + wbase;            \
        gload16(gA0 + (t) * 32, L);                                          \
        gload16(gA1 + (t) * 32, L + 4096); } while (0)
#define STAGE_B(t) do { u16* L = lds + ((t) & 3) * 16384 + wbase;            \
        gload16(gB0 + (t) * 32, L + 8192);                                   \
        gload16(gB1 + (t) * 32, L + 12288); } while (0)

    STAGE_A(0); STAGE_B(0); STAGE_A(1); STAGE_B(1); STAGE_A(2); STAGE_B(2);

    for (int t = 0; t < 132; ++t) {
        if (t < 130)        asm volatile("s_waitcnt vmcnt(8)" ::: "memory");
        else if (t == 130)  asm volatile("s_waitcnt vmcnt(4)" ::: "memory");
        else                asm volatile("s_waitcnt vmcnt(0)" ::: "memory");
        __builtin_amdgcn_s_barrier();
        __builtin_amdgcn_sched_barrier(0);

        const u16* Lb = lds + (t & 3) * 16384;
        s16x8 a0[2][2], a1[2][2], b[2][2];   // [mf-half][kk], [nf][kk]
        // ---- phase 0: read A mf=0,1 (4) + all B (4), stage A-half, MFMA
#pragma unroll
        for (int mf = 0; mf < 2; ++mf) {
            a0[mf][0] = *(const s16x8*)&Lb[abase + mf * 1024 + skk0];
            a0[mf][1] = *(const s16x8*)&Lb[abase + mf * 1024 + skk1];
        }
#pragma unroll
        for (int nf = 0; nf < 2; ++nf) {
            b[nf][0] = *(const s16x8*)&Lb[bbase + nf * 1024 + skk0];
            b[nf][1] = *(const s16x8*)&Lb[bbase + nf * 1024 + skk1];
        }
        if (t + 3 < 132) STAGE_A(t + 3);
        asm volatile("s_waitcnt lgkmcnt(0)" ::: "memory");
        __builtin_amdgcn_sched_barrier(0);
        __builtin_amdgcn_s_setprio(1);
#pragma unroll
        for (int mf = 0; mf < 2; ++mf)
#pragma unroll
            for (int nf = 0; nf < 2; ++nf)
#pragma unroll
                for (int kk = 0; kk < 2; ++kk)
                    acc[mf][nf] = __builtin_amdgcn_mfma_f32_32x32x16_bf16(
                        a0[mf][kk], b[nf][kk], acc[mf][nf], 0, 0, 0);
        __builtin_amdgcn_s_setprio(0);
        __builtin_amdgcn_s_barrier();       // mid-tile phase barrier
        // ---- phase 1: read A mf=2,3, stage B-half, MFMA
#pragma unroll
        for (int mf = 0; mf < 2; ++mf) {
            a1[mf][0] = *(const s16x8*)&Lb[abase + (mf + 2) * 1024 + skk0];
            a1[mf][1] = *(const s16x8*)&Lb[abase + (mf + 2) * 1024 + skk1];
        }
        if (t + 3 < 132) STAGE_B(t + 3);
        asm volatile("s_waitcnt lgkmcnt(0)" ::: "memory");
        __builtin_amdgcn_sched_barrier(0);
        __builtin_amdgcn_s_setprio(1);
#pragma unroll
        for (int mf = 0; mf < 2; ++mf)
#pragma unroll
            for (int nf = 0; nf < 2; ++nf)
#pragma unroll
                for (int kk = 0; kk < 2; ++kk)
                    acc[mf + 2][nf] = __builtin_amdgcn_mfma_f32_32x32x16_bf16(
                        a1[mf][kk], b[nf][kk], acc[mf + 2][nf], 0, 0, 0);
        __builtin_amdgcn_s_setprio(0);
    }
#undef STAGE_A
#undef STAGE_B

    // Epilogue: C/D layout col=lane&31, row=(reg&3)+8*(reg>>2)+4*hk
#pragma unroll
    for (int nf = 0; nf < 2; ++nf) {
        long col = n0 + wc * 64 + nf * 32 + r31;
        float bvv = bias[col];
#pragma unroll
        for (int mf = 0; mf < 4; ++mf) {
            long rowb = m0 + wr * 128 + mf * 32 + 4 * hk;
#pragma unroll
            for (int r = 0; r < 16; ++r) {
                long row = rowb + (r & 3) + 8 * (r >> 2);
                out[row * (long)D_OUT + col] = acc[mf][nf][r] + bvv;
            }
        }
    }
}

// ---------------------------------------------------------------------------
extern "C" void kernel_launch(void* const* d_in, const int* in_sizes, int n_in,
                              void* d_out, int out_size, void* d_ws, size_t ws_size,
                              hipStream_t stream) {
    const float* x  = (const float*)d_in[0];
    const float* bw = (const float*)d_in[1];
    const float* bb = (const float*)d_in[2];
    const float* lA = (const float*)d_in[3];
    const float* lB = (const float*)d_in[4];
    const float* rw = (const float*)d_in[5];
    const float* sc = (const float*)d_in[6];
    float* out = (float*)d_out;

    char* ws = (char*)d_ws;
    u16* Xaug  = (u16*)ws;                      // 8192*4224*2 = 69,206,016 B
    u16* Waug  = (u16*)(ws + 69206016);         // 4096*4224*2 = 34,603,008 B
    u16* A16   = (u16*)(ws + 103809024);        // 128*4096*2  =  1,048,576 B
    float* gates = (float*)(ws + 104857600);    // 8192*8*4    =    262,144 B

    convert_kernel<<<25088, 256, 0, stream>>>(x, bw, lA, lB, Xaug, Waug, A16);
    router_kernel<<<256, 256, 0, stream>>>(x, rw, sc, gates);
    lora_h_kernel<<<256, 256, 0, stream>>>(Xaug, A16, gates);
    main_gemm<<<512, 512, 0, stream>>>(Xaug, Waug, bb, out);
}

// Round 10
// 409.004 us; speedup vs baseline: 1.2433x; 1.2433x over previous
//
#include <hip/hip_runtime.h>
#include <cstdint>

typedef unsigned short u16;
typedef float  f32x4 __attribute__((ext_vector_type(4)));
typedef short  s16x4 __attribute__((ext_vector_type(4)));
typedef short  s16x8 __attribute__((ext_vector_type(8)));

#define D_IN  4096
#define D_OUT 4096
#define RMOE  128
#define KAUG  4224   /* D_IN + RMOE */
#define NTOK  8192   /* B*S = 4*2048 */

__device__ __forceinline__ u16 f2bf(float f) {
    unsigned u = __builtin_bit_cast(unsigned, f);
    unsigned r = u + 0x7fffu + ((u >> 16) & 1u);   // RNE
    return (u16)(r >> 16);
}

__device__ __forceinline__ void gload16(const void* g, void* l) {
    __builtin_amdgcn_global_load_lds(
        (const __attribute__((address_space(1))) void*)g,
        (__attribute__((address_space(3))) void*)l, 16, 0, 0);
}

// ---------------------------------------------------------------------------
// Kernel 1 (ROUND-10, FUSED): x fp32->bf16 into Xaug cols 0..4095 AND the
// fp32 router, in one pass over x (saves one full 128 MB x HBM read).
// 1 token/wave (validated structure); accumulation order + butterfly are
// copied VERBATIM from the round-3..8 router => identical fp32 numerics.
// ---------------------------------------------------------------------------
__global__ __launch_bounds__(256)
void xconv_router_kernel(const float* __restrict__ x, const float* __restrict__ rw,
                         const float* __restrict__ scal,
                         u16* __restrict__ Xaug, float* __restrict__ gates) {
    int wave = threadIdx.x >> 6, lane = threadIdx.x & 63;
    int t = blockIdx.x * 4 + wave;
    const float4* xp = (const float4*)(x + (long)t * D_IN);
    u16* xa = Xaug + (long)t * KAUG;
    float acc[8];
#pragma unroll
    for (int e = 0; e < 8; ++e) acc[e] = 0.f;
#pragma unroll 4
    for (int i = 0; i < 16; ++i) {
        float4 xv = xp[i * 64 + lane];
        s16x4 o;
        o[0] = (short)f2bf(xv.x); o[1] = (short)f2bf(xv.y);
        o[2] = (short)f2bf(xv.z); o[3] = (short)f2bf(xv.w);
        *(s16x4*)(xa + (i * 64 + lane) * 4) = o;
#pragma unroll
        for (int e = 0; e < 8; ++e) {
            float4 wv = ((const float4*)(rw + (long)e * D_IN))[i * 64 + lane];
            acc[e] += xv.x * wv.x + xv.y * wv.y + xv.z * wv.z + xv.w * wv.w;
        }
    }
#pragma unroll
    for (int e = 0; e < 8; ++e) {
#pragma unroll
        for (int off = 32; off > 0; off >>= 1)
            acc[e] += __shfl_xor(acc[e], off, 64);
    }
    if (lane == 0) {
        int i1 = 0; float v1 = acc[0];
#pragma unroll
        for (int e = 1; e < 8; ++e) if (acc[e] > v1) { v1 = acc[e]; i1 = e; }
        int i2 = -1; float v2 = -3.4e38f;
#pragma unroll
        for (int e = 0; e < 8; ++e) if (e != i1 && acc[e] > v2) { v2 = acc[e]; i2 = e; }
        float g1 = 1.f / (1.f + expf(v2 - v1));
        float g2 = 1.f - g1;
        float* gp = gates + (long)t * 8;
#pragma unroll
        for (int e = 0; e < 8; ++e)
            gp[e] = (e == i1) ? g1 * scal[e] : ((e == i2) ? g2 * scal[e] : 0.f);
    }
}

// ---------------------------------------------------------------------------
// Kernel 2 (ROUND-10): remaining conversions — bw, lora_B, lora_A.
// Same 8-elements/thread pattern as the validated convert_kernel.
// ---------------------------------------------------------------------------
__global__ __launch_bounds__(256)
void convert_rest_kernel(const float* __restrict__ bw,
                         const float* __restrict__ lA, const float* __restrict__ lB,
                         u16* __restrict__ Waug, u16* __restrict__ A16) {
    const long nw = (long)D_OUT * D_IN / 8;   // 2,097,152
    const long nb = (long)D_OUT * RMOE / 8;   // 65,536
    long tid = (long)blockIdx.x * 256 + threadIdx.x;
    const float* src; u16* dst;
    if (tid < nw) {
        long e = tid * 8; long row = e >> 12; long col = e & 4095;
        src = bw + e; dst = Waug + row * KAUG + col;
    } else if (tid < nw + nb) {
        long e = (tid - nw) * 8; long row = e >> 7; long col = e & 127;
        src = lB + e; dst = Waug + row * KAUG + D_IN + col;
    } else {
        long e = (tid - nw - nb) * 8;
        src = lA + e; dst = A16 + e;
    }
    float4 a = ((const float4*)src)[0];
    float4 b = ((const float4*)src)[1];
    s16x8 o;
    o[0] = (short)f2bf(a.x); o[1] = (short)f2bf(a.y);
    o[2] = (short)f2bf(a.z); o[3] = (short)f2bf(a.w);
    o[4] = (short)f2bf(b.x); o[5] = (short)f2bf(b.y);
    o[6] = (short)f2bf(b.z); o[7] = (short)f2bf(b.w);
    *(s16x8*)dst = o;
}

// ---------------------------------------------------------------------------
// Kernel 3: h_scaled = (x @ lora_A^T) * gate, bf16 into Xaug cols 4096..4223.
// (unchanged, validated)
// ---------------------------------------------------------------------------
__global__ __launch_bounds__(256)
void lora_h_kernel(u16* __restrict__ Xaug, const u16* __restrict__ A16,
                   const float* __restrict__ gates) {
    __shared__ u16 sX[64 * 32];
    __shared__ u16 sW[64 * 32];
    int tid = threadIdx.x, wave = tid >> 6, lane = tid & 63;
    int bm = blockIdx.x >> 1, bn = blockIdx.x & 1;
    long m0 = (long)bm * 64; int n0 = bn * 64;
    int wr = wave >> 1, wc = wave & 1;
    int c = wave * 64 + lane, row = c >> 2, oct = c & 3;
    const u16* gx = Xaug + (m0 + row) * KAUG + oct * 8;
    const u16* gw = A16 + (long)(n0 + row) * D_IN + oct * 8;
    u16* lx = sX + wave * 512;
    u16* lw = sW + wave * 512;
    int cl = lane & 15, kh = lane >> 4;
    int aoff[2], boff[2];
#pragma unroll
    for (int i = 0; i < 2; ++i) {
        aoff[i] = (wr * 32 + i * 16 + cl) * 32 + kh * 8;
        boff[i] = (wc * 32 + i * 16 + cl) * 32 + kh * 8;
    }
    f32x4 acc[2][2];
#pragma unroll
    for (int i = 0; i < 2; ++i)
#pragma unroll
        for (int j = 0; j < 2; ++j) acc[i][j] = (f32x4){0.f, 0.f, 0.f, 0.f};
    for (int kt = 0; kt < 128; ++kt) {
        __syncthreads();
        gload16(gx, lx); gload16(gw, lw);
        gx += 32; gw += 32;
        __syncthreads();
        s16x8 a[2], b[2];
#pragma unroll
        for (int i = 0; i < 2; ++i) {
            a[i] = *(const s16x8*)&sX[aoff[i]];
            b[i] = *(const s16x8*)&sW[boff[i]];
        }
#pragma unroll
        for (int mi = 0; mi < 2; ++mi)
#pragma unroll
            for (int ni = 0; ni < 2; ++ni)
                acc[mi][ni] = __builtin_amdgcn_mfma_f32_16x16x32_bf16(
                    a[mi], b[ni], acc[mi][ni], 0, 0, 0);
    }
#pragma unroll
    for (int ni = 0; ni < 2; ++ni) {
        int col = n0 + wc * 32 + ni * 16 + cl;
        int g = col >> 4;
#pragma unroll
        for (int mi = 0; mi < 2; ++mi) {
#pragma unroll
            for (int r = 0; r < 4; ++r) {
                long tok = m0 + wr * 32 + mi * 16 + kh * 4 + r;
                float v = acc[mi][ni][r] * gates[tok * 8 + g];
                Xaug[tok * KAUG + D_IN + col] = f2bf(v);
            }
        }
    }
}

// ---------------------------------------------------------------------------
// Kernel 4: main GEMM — EXACT round-6 body (best measured: 297 us,
// conflicts = 0). 256x256 tile, BK=32, 8 waves (2Mx4N), 16x16x32 MFMA,
// 4-deep LDS pipeline, counted vmcnt (T4) + XCD swizzle (T1) + T2 swizzle,
// 2-phase K-step with mid-tile barrier.
// ---------------------------------------------------------------------------
__global__ __launch_bounds__(512, 2)
void main_gemm(const u16* __restrict__ Xaug, const u16* __restrict__ Waug,
               const float* __restrict__ bias, float* __restrict__ out) {
    __shared__ u16 lds[4 * 16384];     // 128 KiB
    const int tid = threadIdx.x;
    const int wave = tid >> 6, lane = tid & 63;
    const int cl = lane & 15, kh = lane >> 4;
    const int wr = wave >> 2, wc = wave & 3;

    // T1: bijective XCD swizzle (512 blocks, 512 % 8 == 0)
    int bid = blockIdx.x;
    int swz = (bid & 7) * 64 + (bid >> 3);
    long m0 = (long)(swz & 31) * 256;   // 32 M-blocks
    long n0 = (long)(swz >> 5) * 256;   // 16 N-blocks

    // staging: thread covers row rA (+128 for second half), 8-el slot.
    // T2: source slot XOR'd by ((row>>1)&3) — permutation within the row.
    const int rA = tid >> 2;
    const int sl = (((tid & 3) ^ ((tid >> 3) & 3))) * 8;
    const u16* gA0 = Xaug + (m0 + rA) * KAUG + sl;
    const u16* gA1 = Xaug + (m0 + 128 + rA) * KAUG + sl;
    const u16* gB0 = Waug + (n0 + rA) * KAUG + sl;
    const u16* gB1 = Waug + (n0 + 128 + rA) * KAUG + sl;
    const int wbase = wave * 512;       // wave-uniform LDS base (el)

    // T2 read side: slot kh ^ ((row>>1)&3); row ≡ cl (mod 16) in all frags.
    const int swk = (kh ^ ((cl >> 1) & 3)) * 8;
    const int aob = (wr * 128 + cl) * 32 + swk;
    const int bob = 8192 + (wc * 64 + cl) * 32 + swk;

    f32x4 acc[8][4];
#pragma unroll
    for (int m = 0; m < 8; ++m)
#pragma unroll
        for (int n = 0; n < 4; ++n) acc[m][n] = (f32x4){0.f, 0.f, 0.f, 0.f};

#define STAGE_A(t) do { u16* L = lds + ((t) & 3) * 16384 + wbase;            \
        gload16(gA0 + (t) * 32, L);                                          \
        gload16(gA1 + (t) * 32, L + 4096); } while (0)
#define STAGE_B(t) do { u16* L = lds + ((t) & 3) * 16384 + wbase;            \
        gload16(gB0 + (t) * 32, L + 8192);                                   \
        gload16(gB1 + (t) * 32, L + 12288); } while (0)

    STAGE_A(0); STAGE_B(0); STAGE_A(1); STAGE_B(1); STAGE_A(2); STAGE_B(2);

    for (int t = 0; t < 132; ++t) {
        if (t < 130)        asm volatile("s_waitcnt vmcnt(8)" ::: "memory");
        else if (t == 130)  asm volatile("s_waitcnt vmcnt(4)" ::: "memory");
        else                asm volatile("s_waitcnt vmcnt(0)" ::: "memory");
        __builtin_amdgcn_s_barrier();
        __builtin_amdgcn_sched_barrier(0);

        const u16* Lb = lds + (t & 3) * 16384;
        s16x8 av[8], bv[4];
        // ---- phase 0: read A0-3 + all B, stage A-half of t+3, MFMA m0-3
#pragma unroll
        for (int m = 0; m < 4; ++m) av[m] = *(const s16x8*)&Lb[aob + m * 512];
#pragma unroll
        for (int n = 0; n < 4; ++n) bv[n] = *(const s16x8*)&Lb[bob + n * 512];
        if (t + 3 < 132) STAGE_A(t + 3);
        asm volatile("s_waitcnt lgkmcnt(0)" ::: "memory");
        __builtin_amdgcn_sched_barrier(0);
        __builtin_amdgcn_s_setprio(1);
#pragma unroll
        for (int m = 0; m < 4; ++m)
#pragma unroll
            for (int n = 0; n < 4; ++n)
                acc[m][n] = __builtin_amdgcn_mfma_f32_16x16x32_bf16(
                    av[m], bv[n], acc[m][n], 0, 0, 0);
        __builtin_amdgcn_s_setprio(0);
        __builtin_amdgcn_s_barrier();       // mid-tile phase barrier
        // ---- phase 1: read A4-7, stage B-half of t+3, MFMA m4-7
#pragma unroll
        for (int m = 4; m < 8; ++m) av[m] = *(const s16x8*)&Lb[aob + m * 512];
        if (t + 3 < 132) STAGE_B(t + 3);
        asm volatile("s_waitcnt lgkmcnt(0)" ::: "memory");
        __builtin_amdgcn_sched_barrier(0);
        __builtin_amdgcn_s_setprio(1);
#pragma unroll
        for (int m = 4; m < 8; ++m)
#pragma unroll
            for (int n = 0; n < 4; ++n)
                acc[m][n] = __builtin_amdgcn_mfma_f32_16x16x32_bf16(
                    av[m], bv[n], acc[m][n], 0, 0, 0);
        __builtin_amdgcn_s_setprio(0);
    }
#undef STAGE_A
#undef STAGE_B

#pragma unroll
    for (int n = 0; n < 4; ++n) {
        long col = n0 + wc * 64 + n * 16 + cl;
        float bvv = bias[col];
#pragma unroll
        for (int m = 0; m < 8; ++m) {
            long row = m0 + wr * 128 + m * 16 + kh * 4;
#pragma unroll
            for (int r = 0; r < 4; ++r)
                out[(row + r) * (long)D_OUT + col] = acc[m][n][r] + bvv;
        }
    }
}

// ---------------------------------------------------------------------------
extern "C" void kernel_launch(void* const* d_in, const int* in_sizes, int n_in,
                              void* d_out, int out_size, void* d_ws, size_t ws_size,
                              hipStream_t stream) {
    const float* x  = (const float*)d_in[0];
    const float* bw = (const float*)d_in[1];
    const float* bb = (const float*)d_in[2];
    const float* lA = (const float*)d_in[3];
    const float* lB = (const float*)d_in[4];
    const float* rw = (const float*)d_in[5];
    const float* sc = (const float*)d_in[6];
    float* out = (float*)d_out;

    char* ws = (char*)d_ws;
    u16* Xaug  = (u16*)ws;                      // 8192*4224*2 = 69,206,016 B
    u16* Waug  = (u16*)(ws + 69206016);         // 4096*4224*2 = 34,603,008 B
    u16* A16   = (u16*)(ws + 103809024);        // 128*4096*2  =  1,048,576 B
    float* gates = (float*)(ws + 104857600);    // 8192*8*4    =    262,144 B

    xconv_router_kernel<<<2048, 256, 0, stream>>>(x, rw, sc, Xaug, gates);
    convert_rest_kernel<<<8704, 256, 0, stream>>>(bw, lA, lB, Waug, A16);
    lora_h_kernel<<<256, 256, 0, stream>>>(Xaug, A16, gates);
    main_gemm<<<512, 512, 0, stream>>>(Xaug, Waug, bb, out);
}

// Round 12
// 403.389 us; speedup vs baseline: 1.2606x; 1.0139x over previous
//
#include <hip/hip_runtime.h>
#include <cstdint>

typedef unsigned short u16;
typedef float  f32x4 __attribute__((ext_vector_type(4)));
typedef short  s16x4 __attribute__((ext_vector_type(4)));
typedef short  s16x8 __attribute__((ext_vector_type(8)));

#define D_IN  4096
#define D_OUT 4096
#define RMOE  128
#define KAUG  4224   /* D_IN + RMOE */
#define NTOK  8192   /* B*S = 4*2048 */

__device__ __forceinline__ u16 f2bf(float f) {
    unsigned u = __builtin_bit_cast(unsigned, f);
    unsigned r = u + 0x7fffu + ((u >> 16) & 1u);   // RNE
    return (u16)(r >> 16);
}

__device__ __forceinline__ void gload16(const void* g, void* l) {
    __builtin_amdgcn_global_load_lds(
        (const __attribute__((address_space(1))) void*)g,
        (__attribute__((address_space(3))) void*)l, 16, 0, 0);
}

// ---------------------------------------------------------------------------
// Kernel 1 (FUSED, validated R10): x fp32->bf16 into Xaug cols 0..4095 AND
// the fp32 router in one pass over x. Router numerics identical to the
// validated 1-token/wave router.
// ---------------------------------------------------------------------------
__global__ __launch_bounds__(256)
void xconv_router_kernel(const float* __restrict__ x, const float* __restrict__ rw,
                         const float* __restrict__ scal,
                         u16* __restrict__ Xaug, float* __restrict__ gates) {
    int wave = threadIdx.x >> 6, lane = threadIdx.x & 63;
    int t = blockIdx.x * 4 + wave;
    const float4* xp = (const float4*)(x + (long)t * D_IN);
    u16* xa = Xaug + (long)t * KAUG;
    float acc[8];
#pragma unroll
    for (int e = 0; e < 8; ++e) acc[e] = 0.f;
#pragma unroll 4
    for (int i = 0; i < 16; ++i) {
        float4 xv = xp[i * 64 + lane];
        s16x4 o;
        o[0] = (short)f2bf(xv.x); o[1] = (short)f2bf(xv.y);
        o[2] = (short)f2bf(xv.z); o[3] = (short)f2bf(xv.w);
        *(s16x4*)(xa + (i * 64 + lane) * 4) = o;
#pragma unroll
        for (int e = 0; e < 8; ++e) {
            float4 wv = ((const float4*)(rw + (long)e * D_IN))[i * 64 + lane];
            acc[e] += xv.x * wv.x + xv.y * wv.y + xv.z * wv.z + xv.w * wv.w;
        }
    }
#pragma unroll
    for (int e = 0; e < 8; ++e) {
#pragma unroll
        for (int off = 32; off > 0; off >>= 1)
            acc[e] += __shfl_xor(acc[e], off, 64);
    }
    if (lane == 0) {
        int i1 = 0; float v1 = acc[0];
#pragma unroll
        for (int e = 1; e < 8; ++e) if (acc[e] > v1) { v1 = acc[e]; i1 = e; }
        int i2 = -1; float v2 = -3.4e38f;
#pragma unroll
        for (int e = 0; e < 8; ++e) if (e != i1 && acc[e] > v2) { v2 = acc[e]; i2 = e; }
        float g1 = 1.f / (1.f + expf(v2 - v1));
        float g2 = 1.f - g1;
        float* gp = gates + (long)t * 8;
#pragma unroll
        for (int e = 0; e < 8; ++e)
            gp[e] = (e == i1) ? g1 * scal[e] : ((e == i2) ? g2 * scal[e] : 0.f);
    }
}

// ---------------------------------------------------------------------------
// Kernel 2 (validated R10): remaining conversions — bw, lora_B, lora_A.
// ---------------------------------------------------------------------------
__global__ __launch_bounds__(256)
void convert_rest_kernel(const float* __restrict__ bw,
                         const float* __restrict__ lA, const float* __restrict__ lB,
                         u16* __restrict__ Waug, u16* __restrict__ A16) {
    const long nw = (long)D_OUT * D_IN / 8;   // 2,097,152
    const long nb = (long)D_OUT * RMOE / 8;   // 65,536
    long tid = (long)blockIdx.x * 256 + threadIdx.x;
    const float* src; u16* dst;
    if (tid < nw) {
        long e = tid * 8; long row = e >> 12; long col = e & 4095;
        src = bw + e; dst = Waug + row * KAUG + col;
    } else if (tid < nw + nb) {
        long e = (tid - nw) * 8; long row = e >> 7; long col = e & 127;
        src = lB + e; dst = Waug + row * KAUG + D_IN + col;
    } else {
        long e = (tid - nw - nb) * 8;
        src = lA + e; dst = A16 + e;
    }
    float4 a = ((const float4*)src)[0];
    float4 b = ((const float4*)src)[1];
    s16x8 o;
    o[0] = (short)f2bf(a.x); o[1] = (short)f2bf(a.y);
    o[2] = (short)f2bf(a.z); o[3] = (short)f2bf(a.w);
    o[4] = (short)f2bf(b.x); o[5] = (short)f2bf(b.y);
    o[6] = (short)f2bf(b.z); o[7] = (short)f2bf(b.w);
    *(s16x8*)dst = o;
}

// ---------------------------------------------------------------------------
// Kernel 3: h_scaled = (x @ lora_A^T) * gate, bf16 into Xaug cols 4096..4223.
// (unchanged, validated)
// ---------------------------------------------------------------------------
__global__ __launch_bounds__(256)
void lora_h_kernel(u16* __restrict__ Xaug, const u16* __restrict__ A16,
                   const float* __restrict__ gates) {
    __shared__ u16 sX[64 * 32];
    __shared__ u16 sW[64 * 32];
    int tid = threadIdx.x, wave = tid >> 6, lane = tid & 63;
    int bm = blockIdx.x >> 1, bn = blockIdx.x & 1;
    long m0 = (long)bm * 64; int n0 = bn * 64;
    int wr = wave >> 1, wc = wave & 1;
    int c = wave * 64 + lane, row = c >> 2, oct = c & 3;
    const u16* gx = Xaug + (m0 + row) * KAUG + oct * 8;
    const u16* gw = A16 + (long)(n0 + row) * D_IN + oct * 8;
    u16* lx = sX + wave * 512;
    u16* lw = sW + wave * 512;
    int cl = lane & 15, kh = lane >> 4;
    int aoff[2], boff[2];
#pragma unroll
    for (int i = 0; i < 2; ++i) {
        aoff[i] = (wr * 32 + i * 16 + cl) * 32 + kh * 8;
        boff[i] = (wc * 32 + i * 16 + cl) * 32 + kh * 8;
    }
    f32x4 acc[2][2];
#pragma unroll
    for (int i = 0; i < 2; ++i)
#pragma unroll
        for (int j = 0; j < 2; ++j) acc[i][j] = (f32x4){0.f, 0.f, 0.f, 0.f};
    for (int kt = 0; kt < 128; ++kt) {
        __syncthreads();
        gload16(gx, lx); gload16(gw, lw);
        gx += 32; gw += 32;
        __syncthreads();
        s16x8 a[2], b[2];
#pragma unroll
        for (int i = 0; i < 2; ++i) {
            a[i] = *(const s16x8*)&sX[aoff[i]];
            b[i] = *(const s16x8*)&sW[boff[i]];
        }
#pragma unroll
        for (int mi = 0; mi < 2; ++mi)
#pragma unroll
            for (int ni = 0; ni < 2; ++ni)
                acc[mi][ni] = __builtin_amdgcn_mfma_f32_16x16x32_bf16(
                    a[mi], b[ni], acc[mi][ni], 0, 0, 0);
    }
#pragma unroll
    for (int ni = 0; ni < 2; ++ni) {
        int col = n0 + wc * 32 + ni * 16 + cl;
        int g = col >> 4;
#pragma unroll
        for (int mi = 0; mi < 2; ++mi) {
#pragma unroll
            for (int r = 0; r < 4; ++r) {
                long tok = m0 + wr * 32 + mi * 16 + kh * 4 + r;
                float v = acc[mi][ni][r] * gates[tok * 8 + g];
                Xaug[tok * KAUG + D_IN + col] = f2bf(v);
            }
        }
    }
}

// ---------------------------------------------------------------------------
// Kernel 4: main GEMM, 256x256 tile, BK=32, 8 waves (2Mx4N), 4-deep LDS
// pipeline, counted vmcnt (T4) + XCD swizzle (T1) + T2 LDS swizzle.
//
// ROUND-11 CHANGE (intra-wave wait structure only): single barrier/tile;
// ALL 12 ds_reads (cluster-0 operands first) + both stages issued up front;
// sched_barrier(0) fences pin 3 regions {reads+stages}/{MFMA m0-3}/{MFMA
// m4-7}; NO manual lgkm drains — the compiler inserts COUNTED lgkmcnt per
// its emitted order (m97 r109), so cluster-0 starts after its 8 reads while
// A4-7's reads service under cluster-0's MFMAs (LDS || MFMA overlap).
//
// Inter-tile skeleton IDENTICAL to validated R5-R10: counted vmcnt BEFORE
// the tile-top barrier; STAGE(t+3) writes buf[(t-1)&3], whose readers all
// completed (full lgkm drain implied by last cluster's operand waits)
// before barrier(t).
// ---------------------------------------------------------------------------
__global__ __launch_bounds__(512, 2)
void main_gemm(const u16* __restrict__ Xaug, const u16* __restrict__ Waug,
               const float* __restrict__ bias, float* __restrict__ out) {
    __shared__ u16 lds[4 * 16384];     // 128 KiB
    const int tid = threadIdx.x;
    const int wave = tid >> 6, lane = tid & 63;
    const int cl = lane & 15, kh = lane >> 4;
    const int wr = wave >> 2, wc = wave & 3;

    // T1: bijective XCD swizzle (512 blocks, 512 % 8 == 0)
    int bid = blockIdx.x;
    int swz = (bid & 7) * 64 + (bid >> 3);
    long m0 = (long)(swz & 31) * 256;   // 32 M-blocks
    long n0 = (long)(swz >> 5) * 256;   // 16 N-blocks

    // staging: thread covers row rA (+128 for second half), 8-el slot.
    // T2: source slot XOR'd by ((row>>1)&3) — permutation within the row.
    const int rA = tid >> 2;
    const int sl = (((tid & 3) ^ ((tid >> 3) & 3))) * 8;
    const u16* gA0 = Xaug + (m0 + rA) * KAUG + sl;
    const u16* gA1 = Xaug + (m0 + 128 + rA) * KAUG + sl;
    const u16* gB0 = Waug + (n0 + rA) * KAUG + sl;
    const u16* gB1 = Waug + (n0 + 128 + rA) * KAUG + sl;
    const int wbase = wave * 512;       // wave-uniform LDS base (el)

    // T2 read side: slot kh ^ ((row>>1)&3); row ≡ cl (mod 16) in all frags.
    const int swk = (kh ^ ((cl >> 1) & 3)) * 8;
    const int aob = (wr * 128 + cl) * 32 + swk;
    const int bob = 8192 + (wc * 64 + cl) * 32 + swk;

    f32x4 acc[8][4];
#pragma unroll
    for (int m = 0; m < 8; ++m)
#pragma unroll
        for (int n = 0; n < 4; ++n) acc[m][n] = (f32x4){0.f, 0.f, 0.f, 0.f};

#define STAGE_A(t) do { u16* L = lds + ((t) & 3) * 16384 + wbase;            \
        gload16(gA0 + (t) * 32, L);                                          \
        gload16(gA1 + (t) * 32, L + 4096); } while (0)
#define STAGE_B(t) do { u16* L = lds + ((t) & 3) * 16384 + wbase;            \
        gload16(gB0 + (t) * 32, L + 8192);                                   \
        gload16(gB1 + (t) * 32, L + 12288); } while (0)

    STAGE_A(0); STAGE_B(0); STAGE_A(1); STAGE_B(1); STAGE_A(2); STAGE_B(2);

    for (int t = 0; t < 132; ++t) {
        if (t < 130)        asm volatile("s_waitcnt vmcnt(8)" ::: "memory");
        else if (t == 130)  asm volatile("s_waitcnt vmcnt(4)" ::: "memory");
        else                asm volatile("s_waitcnt vmcnt(0)" ::: "memory");
        __builtin_amdgcn_s_barrier();
        __builtin_amdgcn_sched_barrier(0);

        const u16* Lb = lds + (t & 3) * 16384;
        s16x8 av[8], bv[4];
        // ---- region 0: all reads (cluster-0 operands first) + both stages
#pragma unroll
        for (int m = 0; m < 4; ++m) av[m] = *(const s16x8*)&Lb[aob + m * 512];
#pragma unroll
        for (int n = 0; n < 4; ++n) bv[n] = *(const s16x8*)&Lb[bob + n * 512];
        if (t + 3 < 132) { STAGE_A(t + 3); STAGE_B(t + 3); }
#pragma unroll
        for (int m = 4; m < 8; ++m) av[m] = *(const s16x8*)&Lb[aob + m * 512];
        __builtin_amdgcn_sched_barrier(0);
        // ---- region 1: MFMA cluster 0 (m0-3) — compiler emits counted
        //      lgkmcnt for its operands; A4-7 reads service underneath.
        __builtin_amdgcn_s_setprio(1);
#pragma unroll
        for (int m = 0; m < 4; ++m)
#pragma unroll
            for (int n = 0; n < 4; ++n)
                acc[m][n] = __builtin_amdgcn_mfma_f32_16x16x32_bf16(
                    av[m], bv[n], acc[m][n], 0, 0, 0);
        __builtin_amdgcn_s_setprio(0);
        __builtin_amdgcn_sched_barrier(0);
        // ---- region 2: MFMA cluster 1 (m4-7)
        __builtin_amdgcn_s_setprio(1);
#pragma unroll
        for (int m = 4; m < 8; ++m)
#pragma unroll
            for (int n = 0; n < 4; ++n)
                acc[m][n] = __builtin_amdgcn_mfma_f32_16x16x32_bf16(
                    av[m], bv[n], acc[m][n], 0, 0, 0);
        __builtin_amdgcn_s_setprio(0);
    }
#undef STAGE_A
#undef STAGE_B

#pragma unroll
    for (int n = 0; n < 4; ++n) {
        long col = n0 + wc * 64 + n * 16 + cl;
        float bvv = bias[col];
#pragma unroll
        for (int m = 0; m < 8; ++m) {
            long row = m0 + wr * 128 + m * 16 + kh * 4;
#pragma unroll
            for (int r = 0; r < 4; ++r)
                out[(row + r) * (long)D_OUT + col] = acc[m][n][r] + bvv;
        }
    }
}

// ---------------------------------------------------------------------------
extern "C" void kernel_launch(void* const* d_in, const int* in_sizes, int n_in,
                              void* d_out, int out_size, void* d_ws, size_t ws_size,
                              hipStream_t stream) {
    const float* x  = (const float*)d_in[0];
    const float* bw = (const float*)d_in[1];
    const float* bb = (const float*)d_in[2];
    const float* lA = (const float*)d_in[3];
    const float* lB = (const float*)d_in[4];
    const float* rw = (const float*)d_in[5];
    const float* sc = (const float*)d_in[6];
    float* out = (float*)d_out;

    char* ws = (char*)d_ws;
    u16* Xaug  = (u16*)ws;                      // 8192*4224*2 = 69,206,016 B
    u16* Waug  = (u16*)(ws + 69206016);         // 4096*4224*2 = 34,603,008 B
    u16* A16   = (u16*)(ws + 103809024);        // 128*4096*2  =  1,048,576 B
    float* gates = (float*)(ws + 104857600);    // 8192*8*4    =    262,144 B

    xconv_router_kernel<<<2048, 256, 0, stream>>>(x, rw, sc, Xaug, gates);
    convert_rest_kernel<<<8704, 256, 0, stream>>>(bw, lA, lB, Waug, A16);
    lora_h_kernel<<<256, 256, 0, stream>>>(Xaug, A16, gates);
    main_gemm<<<512, 512, 0, stream>>>(Xaug, Waug, bb, out);
}

// Round 13
// 402.034 us; speedup vs baseline: 1.2649x; 1.0034x over previous
//
#include <hip/hip_runtime.h>
#include <cstdint>

typedef unsigned short u16;
typedef float  f32x4 __attribute__((ext_vector_type(4)));
typedef short  s16x4 __attribute__((ext_vector_type(4)));
typedef short  s16x8 __attribute__((ext_vector_type(8)));

#define D_IN  4096
#define D_OUT 4096
#define RMOE  128
#define KAUG  4224   /* D_IN + RMOE */
#define NTOK  8192   /* B*S = 4*2048 */

__device__ __forceinline__ u16 f2bf(float f) {
    unsigned u = __builtin_bit_cast(unsigned, f);
    unsigned r = u + 0x7fffu + ((u >> 16) & 1u);   // RNE
    return (u16)(r >> 16);
}

__device__ __forceinline__ void gload16(const void* g, void* l) {
    __builtin_amdgcn_global_load_lds(
        (const __attribute__((address_space(1))) void*)g,
        (__attribute__((address_space(3))) void*)l, 16, 0, 0);
}

// ---------------------------------------------------------------------------
// Kernel 1 (FUSED, validated R10): x fp32->bf16 into Xaug cols 0..4095 AND
// the fp32 router in one pass over x.
// ---------------------------------------------------------------------------
__global__ __launch_bounds__(256)
void xconv_router_kernel(const float* __restrict__ x, const float* __restrict__ rw,
                         const float* __restrict__ scal,
                         u16* __restrict__ Xaug, float* __restrict__ gates) {
    int wave = threadIdx.x >> 6, lane = threadIdx.x & 63;
    int t = blockIdx.x * 4 + wave;
    const float4* xp = (const float4*)(x + (long)t * D_IN);
    u16* xa = Xaug + (long)t * KAUG;
    float acc[8];
#pragma unroll
    for (int e = 0; e < 8; ++e) acc[e] = 0.f;
#pragma unroll 4
    for (int i = 0; i < 16; ++i) {
        float4 xv = xp[i * 64 + lane];
        s16x4 o;
        o[0] = (short)f2bf(xv.x); o[1] = (short)f2bf(xv.y);
        o[2] = (short)f2bf(xv.z); o[3] = (short)f2bf(xv.w);
        *(s16x4*)(xa + (i * 64 + lane) * 4) = o;
#pragma unroll
        for (int e = 0; e < 8; ++e) {
            float4 wv = ((const float4*)(rw + (long)e * D_IN))[i * 64 + lane];
            acc[e] += xv.x * wv.x + xv.y * wv.y + xv.z * wv.z + xv.w * wv.w;
        }
    }
#pragma unroll
    for (int e = 0; e < 8; ++e) {
#pragma unroll
        for (int off = 32; off > 0; off >>= 1)
            acc[e] += __shfl_xor(acc[e], off, 64);
    }
    if (lane == 0) {
        int i1 = 0; float v1 = acc[0];
#pragma unroll
        for (int e = 1; e < 8; ++e) if (acc[e] > v1) { v1 = acc[e]; i1 = e; }
        int i2 = -1; float v2 = -3.4e38f;
#pragma unroll
        for (int e = 0; e < 8; ++e) if (e != i1 && acc[e] > v2) { v2 = acc[e]; i2 = e; }
        float g1 = 1.f / (1.f + expf(v2 - v1));
        float g2 = 1.f - g1;
        float* gp = gates + (long)t * 8;
#pragma unroll
        for (int e = 0; e < 8; ++e)
            gp[e] = (e == i1) ? g1 * scal[e] : ((e == i2) ? g2 * scal[e] : 0.f);
    }
}

// ---------------------------------------------------------------------------
// Kernel 2 (validated R10): remaining conversions — bw, lora_B, lora_A.
// ---------------------------------------------------------------------------
__global__ __launch_bounds__(256)
void convert_rest_kernel(const float* __restrict__ bw,
                         const float* __restrict__ lA, const float* __restrict__ lB,
                         u16* __restrict__ Waug, u16* __restrict__ A16) {
    const long nw = (long)D_OUT * D_IN / 8;   // 2,097,152
    const long nb = (long)D_OUT * RMOE / 8;   // 65,536
    long tid = (long)blockIdx.x * 256 + threadIdx.x;
    const float* src; u16* dst;
    if (tid < nw) {
        long e = tid * 8; long row = e >> 12; long col = e & 4095;
        src = bw + e; dst = Waug + row * KAUG + col;
    } else if (tid < nw + nb) {
        long e = (tid - nw) * 8; long row = e >> 7; long col = e & 127;
        src = lB + e; dst = Waug + row * KAUG + D_IN + col;
    } else {
        long e = (tid - nw - nb) * 8;
        src = lA + e; dst = A16 + e;
    }
    float4 a = ((const float4*)src)[0];
    float4 b = ((const float4*)src)[1];
    s16x8 o;
    o[0] = (short)f2bf(a.x); o[1] = (short)f2bf(a.y);
    o[2] = (short)f2bf(a.z); o[3] = (short)f2bf(a.w);
    o[4] = (short)f2bf(b.x); o[5] = (short)f2bf(b.y);
    o[6] = (short)f2bf(b.z); o[7] = (short)f2bf(b.w);
    *(s16x8*)dst = o;
}

// ---------------------------------------------------------------------------
// Kernel 3: h_scaled = (x @ lora_A^T) * gate, bf16 into Xaug cols 4096..4223.
// (unchanged, validated)
// ---------------------------------------------------------------------------
__global__ __launch_bounds__(256)
void lora_h_kernel(u16* __restrict__ Xaug, const u16* __restrict__ A16,
                   const float* __restrict__ gates) {
    __shared__ u16 sX[64 * 32];
    __shared__ u16 sW[64 * 32];
    int tid = threadIdx.x, wave = tid >> 6, lane = tid & 63;
    int bm = blockIdx.x >> 1, bn = blockIdx.x & 1;
    long m0 = (long)bm * 64; int n0 = bn * 64;
    int wr = wave >> 1, wc = wave & 1;
    int c = wave * 64 + lane, row = c >> 2, oct = c & 3;
    const u16* gx = Xaug + (m0 + row) * KAUG + oct * 8;
    const u16* gw = A16 + (long)(n0 + row) * D_IN + oct * 8;
    u16* lx = sX + wave * 512;
    u16* lw = sW + wave * 512;
    int cl = lane & 15, kh = lane >> 4;
    int aoff[2], boff[2];
#pragma unroll
    for (int i = 0; i < 2; ++i) {
        aoff[i] = (wr * 32 + i * 16 + cl) * 32 + kh * 8;
        boff[i] = (wc * 32 + i * 16 + cl) * 32 + kh * 8;
    }
    f32x4 acc[2][2];
#pragma unroll
    for (int i = 0; i < 2; ++i)
#pragma unroll
        for (int j = 0; j < 2; ++j) acc[i][j] = (f32x4){0.f, 0.f, 0.f, 0.f};
    for (int kt = 0; kt < 128; ++kt) {
        __syncthreads();
        gload16(gx, lx); gload16(gw, lw);
        gx += 32; gw += 32;
        __syncthreads();
        s16x8 a[2], b[2];
#pragma unroll
        for (int i = 0; i < 2; ++i) {
            a[i] = *(const s16x8*)&sX[aoff[i]];
            b[i] = *(const s16x8*)&sW[boff[i]];
        }
#pragma unroll
        for (int mi = 0; mi < 2; ++mi)
#pragma unroll
            for (int ni = 0; ni < 2; ++ni)
                acc[mi][ni] = __builtin_amdgcn_mfma_f32_16x16x32_bf16(
                    a[mi], b[ni], acc[mi][ni], 0, 0, 0);
    }
#pragma unroll
    for (int ni = 0; ni < 2; ++ni) {
        int col = n0 + wc * 32 + ni * 16 + cl;
        int g = col >> 4;
#pragma unroll
        for (int mi = 0; mi < 2; ++mi) {
#pragma unroll
            for (int r = 0; r < 4; ++r) {
                long tok = m0 + wr * 32 + mi * 16 + kh * 4 + r;
                float v = acc[mi][ni][r] * gates[tok * 8 + g];
                Xaug[tok * KAUG + D_IN + col] = f2bf(v);
            }
        }
    }
}

// ---------------------------------------------------------------------------
// Kernel 4: main GEMM, 256x256 tile, BK=32, 8 waves (2Mx4N), 4-deep LDS
// pipeline, counted vmcnt (T4) + XCD swizzle (T1) + T2 LDS swizzle.
//
// ROUND-13 CHANGE: REGISTER-LEVEL READ-AHEAD. During tile t, issue tile
// t+1's 12 ds_reads into the alternate register set (buf[(t+1)&3] data is
// already resident — staged 3 tiles ahead, landed per vmcnt). Then
// lgkmcnt(12) waits only for tile-t's reads (issued a full iteration ago,
// ~free) and the 32 MFMAs run while t+1's reads service underneath.
// Two named register sets via 2x-unrolled loop (rule #20).
//
// Ledger (same safety argument as validated R5-R12 skeleton, shifted one
// tile): STAGE(t+3) writes buf[(t-1)&3]; tile t-1's reads (issued half t-2)
// were lgkm-drained before MFMA(t-1) in every wave, and barrier(t) orders
// all of that before the stage. Reads of buf[(t+1)&3] vs its next
// overwrite (stage at t+2): drained at half t+1's lgkmcnt + barrier(t+2).
// vmcnt ladder (4 loads staged/tile): steady vmcnt(4); t=130 vmcnt(0);
// t=131 no read, lgkmcnt(0) before the final MFMA.
// ---------------------------------------------------------------------------
__global__ __launch_bounds__(512, 2)
void main_gemm(const u16* __restrict__ Xaug, const u16* __restrict__ Waug,
               const float* __restrict__ bias, float* __restrict__ out) {
    __shared__ u16 lds[4 * 16384];     // 128 KiB
    const int tid = threadIdx.x;
    const int wave = tid >> 6, lane = tid & 63;
    const int cl = lane & 15, kh = lane >> 4;
    const int wr = wave >> 2, wc = wave & 3;

    // T1: bijective XCD swizzle (512 blocks, 512 % 8 == 0)
    int bid = blockIdx.x;
    int swz = (bid & 7) * 64 + (bid >> 3);
    long m0 = (long)(swz & 31) * 256;   // 32 M-blocks
    long n0 = (long)(swz >> 5) * 256;   // 16 N-blocks

    // staging: thread covers row rA (+128 for second half), 8-el slot.
    // T2: source slot XOR'd by ((row>>1)&3) — permutation within the row.
    const int rA = tid >> 2;
    const int sl = (((tid & 3) ^ ((tid >> 3) & 3))) * 8;
    const u16* gA0 = Xaug + (m0 + rA) * KAUG + sl;
    const u16* gA1 = Xaug + (m0 + 128 + rA) * KAUG + sl;
    const u16* gB0 = Waug + (n0 + rA) * KAUG + sl;
    const u16* gB1 = Waug + (n0 + 128 + rA) * KAUG + sl;
    const int wbase = wave * 512;       // wave-uniform LDS base (el)

    // T2 read side: slot kh ^ ((row>>1)&3); row ≡ cl (mod 16) in all frags.
    const int swk = (kh ^ ((cl >> 1) & 3)) * 8;
    const int aob = (wr * 128 + cl) * 32 + swk;
    const int bob = 8192 + (wc * 64 + cl) * 32 + swk;

    f32x4 acc[8][4];
#pragma unroll
    for (int m = 0; m < 8; ++m)
#pragma unroll
        for (int n = 0; n < 4; ++n) acc[m][n] = (f32x4){0.f, 0.f, 0.f, 0.f};

#define STAGE(t) do { u16* L = lds + ((t) & 3) * 16384 + wbase;              \
        gload16(gA0 + (t) * 32, L);                                          \
        gload16(gA1 + (t) * 32, L + 4096);                                   \
        gload16(gB0 + (t) * 32, L + 8192);                                   \
        gload16(gB1 + (t) * 32, L + 12288); } while (0)
#define READL(av, bv, Lb) do {                                               \
        _Pragma("unroll")                                                    \
        for (int m_ = 0; m_ < 8; ++m_)                                       \
            av[m_] = *(const s16x8*)&(Lb)[aob + m_ * 512];                   \
        _Pragma("unroll")                                                    \
        for (int n_ = 0; n_ < 4; ++n_)                                       \
            bv[n_] = *(const s16x8*)&(Lb)[bob + n_ * 512]; } while (0)
#define DOMFMA(av, bv) do {                                                  \
        __builtin_amdgcn_s_setprio(1);                                       \
        _Pragma("unroll")                                                    \
        for (int m_ = 0; m_ < 8; ++m_)                                       \
            _Pragma("unroll")                                                \
            for (int n_ = 0; n_ < 4; ++n_)                                   \
                acc[m_][n_] = __builtin_amdgcn_mfma_f32_16x16x32_bf16(       \
                    av[m_], bv[n_], acc[m_][n_], 0, 0, 0);                   \
        __builtin_amdgcn_s_setprio(0); } while (0)

    s16x8 av0[8], bv0[4], av1[8], bv1[4];

    STAGE(0); STAGE(1); STAGE(2);                 // 12 loads in flight
    asm volatile("s_waitcnt vmcnt(8)" ::: "memory");   // tile 0 landed
    __builtin_amdgcn_s_barrier();
    __builtin_amdgcn_sched_barrier(0);
    READL(av0, bv0, (lds + 0));                   // tile 0 operands (12 reads)

    for (int u = 0; u < 66; ++u) {
        const int tA = 2 * u, tB = 2 * u + 1;
        // ---- half A: compute tile tA from (av0,bv0); read tB into (av1,bv1)
        if (tA <= 128) asm volatile("s_waitcnt vmcnt(4)" ::: "memory");
        else           asm volatile("s_waitcnt vmcnt(0)" ::: "memory");
        __builtin_amdgcn_s_barrier();
        __builtin_amdgcn_sched_barrier(0);
        {
            const u16* Lb = lds + (tB & 3) * 16384;
            READL(av1, bv1, Lb);
            if (tA + 3 < 132) STAGE(tA + 3);
        }
        asm volatile("s_waitcnt lgkmcnt(12)" ::: "memory");  // av0/bv0 done
        __builtin_amdgcn_sched_barrier(0);
        DOMFMA(av0, bv0);
        // ---- half B: compute tile tB from (av1,bv1); read tA+2 into (av0,bv0)
        if (tB < 131) {
            asm volatile("s_waitcnt vmcnt(4)" ::: "memory");  // tB<=129 here
            __builtin_amdgcn_s_barrier();
            __builtin_amdgcn_sched_barrier(0);
            {
                const u16* Lb = lds + ((tB + 1) & 3) * 16384;
                READL(av0, bv0, Lb);
                if (tB + 3 < 132) STAGE(tB + 3);
            }
            asm volatile("s_waitcnt lgkmcnt(12)" ::: "memory");  // av1/bv1 done
            __builtin_amdgcn_sched_barrier(0);
        } else {
            asm volatile("s_waitcnt lgkmcnt(0)" ::: "memory");   // last tile
            __builtin_amdgcn_sched_barrier(0);
        }
        DOMFMA(av1, bv1);
    }
#undef STAGE
#undef READL
#undef DOMFMA

#pragma unroll
    for (int n = 0; n < 4; ++n) {
        long col = n0 + wc * 64 + n * 16 + cl;
        float bvv = bias[col];
#pragma unroll
        for (int m = 0; m < 8; ++m) {
            long row = m0 + wr * 128 + m * 16 + kh * 4;
#pragma unroll
            for (int r = 0; r < 4; ++r)
                out[(row + r) * (long)D_OUT + col] = acc[m][n][r] + bvv;
        }
    }
}

// ---------------------------------------------------------------------------
extern "C" void kernel_launch(void* const* d_in, const int* in_sizes, int n_in,
                              void* d_out, int out_size, void* d_ws, size_t ws_size,
                              hipStream_t stream) {
    const float* x  = (const float*)d_in[0];
    const float* bw = (const float*)d_in[1];
    const float* bb = (const float*)d_in[2];
    const float* lA = (const float*)d_in[3];
    const float* lB = (const float*)d_in[4];
    const float* rw = (const float*)d_in[5];
    const float* sc = (const float*)d_in[6];
    float* out = (float*)d_out;

    char* ws = (char*)d_ws;
    u16* Xaug  = (u16*)ws;                      // 8192*4224*2 = 69,206,016 B
    u16* Waug  = (u16*)(ws + 69206016);         // 4096*4224*2 = 34,603,008 B
    u16* A16   = (u16*)(ws + 103809024);        // 128*4096*2  =  1,048,576 B
    float* gates = (float*)(ws + 104857600);    // 8192*8*4    =    262,144 B

    xconv_router_kernel<<<2048, 256, 0, stream>>>(x, rw, sc, Xaug, gates);
    convert_rest_kernel<<<8704, 256, 0, stream>>>(bw, lA, lB, Waug, A16);
    lora_h_kernel<<<256, 256, 0, stream>>>(Xaug, A16, gates);
    main_gemm<<<512, 512, 0, stream>>>(Xaug, Waug, bb, out);
}

// Round 14
// 399.035 us; speedup vs baseline: 1.2744x; 1.0075x over previous
//
#include <hip/hip_runtime.h>
#include <cstdint>

typedef unsigned short u16;
typedef float  f32x4 __attribute__((ext_vector_type(4)));
typedef short  s16x4 __attribute__((ext_vector_type(4)));
typedef short  s16x8 __attribute__((ext_vector_type(8)));

#define D_IN  4096
#define D_OUT 4096
#define RMOE  128
#define KAUG  4224   /* D_IN + RMOE */
#define NTOK  8192   /* B*S = 4*2048 */

__device__ __forceinline__ u16 f2bf(float f) {
    unsigned u = __builtin_bit_cast(unsigned, f);
    unsigned r = u + 0x7fffu + ((u >> 16) & 1u);   // RNE
    return (u16)(r >> 16);
}

__device__ __forceinline__ void gload16(const void* g, void* l) {
    __builtin_amdgcn_global_load_lds(
        (const __attribute__((address_space(1))) void*)g,
        (__attribute__((address_space(3))) void*)l, 16, 0, 0);
}

// ---------------------------------------------------------------------------
// Kernel 1 (FUSED, validated R10): x fp32->bf16 into Xaug cols 0..4095 AND
// the fp32 router in one pass over x.
// ---------------------------------------------------------------------------
__global__ __launch_bounds__(256)
void xconv_router_kernel(const float* __restrict__ x, const float* __restrict__ rw,
                         const float* __restrict__ scal,
                         u16* __restrict__ Xaug, float* __restrict__ gates) {
    int wave = threadIdx.x >> 6, lane = threadIdx.x & 63;
    int t = blockIdx.x * 4 + wave;
    const float4* xp = (const float4*)(x + (long)t * D_IN);
    u16* xa = Xaug + (long)t * KAUG;
    float acc[8];
#pragma unroll
    for (int e = 0; e < 8; ++e) acc[e] = 0.f;
#pragma unroll 4
    for (int i = 0; i < 16; ++i) {
        float4 xv = xp[i * 64 + lane];
        s16x4 o;
        o[0] = (short)f2bf(xv.x); o[1] = (short)f2bf(xv.y);
        o[2] = (short)f2bf(xv.z); o[3] = (short)f2bf(xv.w);
        *(s16x4*)(xa + (i * 64 + lane) * 4) = o;
#pragma unroll
        for (int e = 0; e < 8; ++e) {
            float4 wv = ((const float4*)(rw + (long)e * D_IN))[i * 64 + lane];
            acc[e] += xv.x * wv.x + xv.y * wv.y + xv.z * wv.z + xv.w * wv.w;
        }
    }
#pragma unroll
    for (int e = 0; e < 8; ++e) {
#pragma unroll
        for (int off = 32; off > 0; off >>= 1)
            acc[e] += __shfl_xor(acc[e], off, 64);
    }
    if (lane == 0) {
        int i1 = 0; float v1 = acc[0];
#pragma unroll
        for (int e = 1; e < 8; ++e) if (acc[e] > v1) { v1 = acc[e]; i1 = e; }
        int i2 = -1; float v2 = -3.4e38f;
#pragma unroll
        for (int e = 0; e < 8; ++e) if (e != i1 && acc[e] > v2) { v2 = acc[e]; i2 = e; }
        float g1 = 1.f / (1.f + expf(v2 - v1));
        float g2 = 1.f - g1;
        float* gp = gates + (long)t * 8;
#pragma unroll
        for (int e = 0; e < 8; ++e)
            gp[e] = (e == i1) ? g1 * scal[e] : ((e == i2) ? g2 * scal[e] : 0.f);
    }
}

// ---------------------------------------------------------------------------
// Kernel 2 (validated R10): remaining conversions — bw, lora_B, lora_A.
// ---------------------------------------------------------------------------
__global__ __launch_bounds__(256)
void convert_rest_kernel(const float* __restrict__ bw,
                         const float* __restrict__ lA, const float* __restrict__ lB,
                         u16* __restrict__ Waug, u16* __restrict__ A16) {
    const long nw = (long)D_OUT * D_IN / 8;   // 2,097,152
    const long nb = (long)D_OUT * RMOE / 8;   // 65,536
    long tid = (long)blockIdx.x * 256 + threadIdx.x;
    const float* src; u16* dst;
    if (tid < nw) {
        long e = tid * 8; long row = e >> 12; long col = e & 4095;
        src = bw + e; dst = Waug + row * KAUG + col;
    } else if (tid < nw + nb) {
        long e = (tid - nw) * 8; long row = e >> 7; long col = e & 127;
        src = lB + e; dst = Waug + row * KAUG + D_IN + col;
    } else {
        long e = (tid - nw - nb) * 8;
        src = lA + e; dst = A16 + e;
    }
    float4 a = ((const float4*)src)[0];
    float4 b = ((const float4*)src)[1];
    s16x8 o;
    o[0] = (short)f2bf(a.x); o[1] = (short)f2bf(a.y);
    o[2] = (short)f2bf(a.z); o[3] = (short)f2bf(a.w);
    o[4] = (short)f2bf(b.x); o[5] = (short)f2bf(b.y);
    o[6] = (short)f2bf(b.z); o[7] = (short)f2bf(b.w);
    *(s16x8*)dst = o;
}

// ---------------------------------------------------------------------------
// Kernel 3: h_scaled = (x @ lora_A^T) * gate, bf16 into Xaug cols 4096..4223.
// (unchanged, validated)
// ---------------------------------------------------------------------------
__global__ __launch_bounds__(256)
void lora_h_kernel(u16* __restrict__ Xaug, const u16* __restrict__ A16,
                   const float* __restrict__ gates) {
    __shared__ u16 sX[64 * 32];
    __shared__ u16 sW[64 * 32];
    int tid = threadIdx.x, wave = tid >> 6, lane = tid & 63;
    int bm = blockIdx.x >> 1, bn = blockIdx.x & 1;
    long m0 = (long)bm * 64; int n0 = bn * 64;
    int wr = wave >> 1, wc = wave & 1;
    int c = wave * 64 + lane, row = c >> 2, oct = c & 3;
    const u16* gx = Xaug + (m0 + row) * KAUG + oct * 8;
    const u16* gw = A16 + (long)(n0 + row) * D_IN + oct * 8;
    u16* lx = sX + wave * 512;
    u16* lw = sW + wave * 512;
    int cl = lane & 15, kh = lane >> 4;
    int aoff[2], boff[2];
#pragma unroll
    for (int i = 0; i < 2; ++i) {
        aoff[i] = (wr * 32 + i * 16 + cl) * 32 + kh * 8;
        boff[i] = (wc * 32 + i * 16 + cl) * 32 + kh * 8;
    }
    f32x4 acc[2][2];
#pragma unroll
    for (int i = 0; i < 2; ++i)
#pragma unroll
        for (int j = 0; j < 2; ++j) acc[i][j] = (f32x4){0.f, 0.f, 0.f, 0.f};
    for (int kt = 0; kt < 128; ++kt) {
        __syncthreads();
        gload16(gx, lx); gload16(gw, lw);
        gx += 32; gw += 32;
        __syncthreads();
        s16x8 a[2], b[2];
#pragma unroll
        for (int i = 0; i < 2; ++i) {
            a[i] = *(const s16x8*)&sX[aoff[i]];
            b[i] = *(const s16x8*)&sW[boff[i]];
        }
#pragma unroll
        for (int mi = 0; mi < 2; ++mi)
#pragma unroll
            for (int ni = 0; ni < 2; ++ni)
                acc[mi][ni] = __builtin_amdgcn_mfma_f32_16x16x32_bf16(
                    a[mi], b[ni], acc[mi][ni], 0, 0, 0);
    }
#pragma unroll
    for (int ni = 0; ni < 2; ++ni) {
        int col = n0 + wc * 32 + ni * 16 + cl;
        int g = col >> 4;
#pragma unroll
        for (int mi = 0; mi < 2; ++mi) {
#pragma unroll
            for (int r = 0; r < 4; ++r) {
                long tok = m0 + wr * 32 + mi * 16 + kh * 4 + r;
                float v = acc[mi][ni][r] * gates[tok * 8 + g];
                Xaug[tok * KAUG + D_IN + col] = f2bf(v);
            }
        }
    }
}

// ---------------------------------------------------------------------------
// Kernel 4: main GEMM, 256x256 tile, BK=32, 8 waves (2Mx4N), 4-deep LDS
// pipeline, counted vmcnt (T4) + XCD swizzle (T1) + T2 LDS swizzle +
// register read-ahead (R13).
//
// ROUND-14 CHANGE (issue placement only): next-tile reads TRICKLED in 4
// groups aligned with 4 MFMA clusters of 8:
//   G0={bv0..3,av0,av1} -> lgkmcnt(6) -> CL(m0,m1) -> G1={av2,av3} ->
//   CL(m2,m3) -> G2 -> CL(m4,m5) -> G3+STAGE -> CL(m6,m7)
// One lgkm wait/tile (6 = G0 outstanding; forces the CURRENT set, read
// during the previous tile, complete). LDS pipe gets reads in cluster-
// aligned groups instead of a 12-read burst -> service overlaps MFMA.
//
// Inter-tile ledger IDENTICAL to validated R13: vmcnt(4/0) BEFORE barrier;
// STAGE(t+3) overwrites buf[(t-1)&3] whose reads completed >=1 barrier
// earlier (enforced by the per-tile lgkm wait).
// ---------------------------------------------------------------------------
__global__ __launch_bounds__(512, 2)
void main_gemm(const u16* __restrict__ Xaug, const u16* __restrict__ Waug,
               const float* __restrict__ bias, float* __restrict__ out) {
    __shared__ u16 lds[4 * 16384];     // 128 KiB
    const int tid = threadIdx.x;
    const int wave = tid >> 6, lane = tid & 63;
    const int cl = lane & 15, kh = lane >> 4;
    const int wr = wave >> 2, wc = wave & 3;

    // T1: bijective XCD swizzle (512 blocks, 512 % 8 == 0)
    int bid = blockIdx.x;
    int swz = (bid & 7) * 64 + (bid >> 3);
    long m0 = (long)(swz & 31) * 256;   // 32 M-blocks
    long n0 = (long)(swz >> 5) * 256;   // 16 N-blocks

    const int rA = tid >> 2;
    const int sl = (((tid & 3) ^ ((tid >> 3) & 3))) * 8;
    const u16* gA0 = Xaug + (m0 + rA) * KAUG + sl;
    const u16* gA1 = Xaug + (m0 + 128 + rA) * KAUG + sl;
    const u16* gB0 = Waug + (n0 + rA) * KAUG + sl;
    const u16* gB1 = Waug + (n0 + 128 + rA) * KAUG + sl;
    const int wbase = wave * 512;       // wave-uniform LDS base (el)

    const int swk = (kh ^ ((cl >> 1) & 3)) * 8;
    const int aob = (wr * 128 + cl) * 32 + swk;
    const int bob = 8192 + (wc * 64 + cl) * 32 + swk;

    f32x4 acc[8][4];
#pragma unroll
    for (int m = 0; m < 8; ++m)
#pragma unroll
        for (int n = 0; n < 4; ++n) acc[m][n] = (f32x4){0.f, 0.f, 0.f, 0.f};

#define STAGE(t) do { u16* L = lds + ((t) & 3) * 16384 + wbase;              \
        gload16(gA0 + (t) * 32, L);                                          \
        gload16(gA1 + (t) * 32, L + 4096);                                   \
        gload16(gB0 + (t) * 32, L + 8192);                                   \
        gload16(gB1 + (t) * 32, L + 12288); } while (0)
#define CL2(av, bv, M) do {                                                  \
        __builtin_amdgcn_s_setprio(1);                                       \
        _Pragma("unroll")                                                    \
        for (int n_ = 0; n_ < 4; ++n_)                                       \
            acc[M][n_] = __builtin_amdgcn_mfma_f32_16x16x32_bf16(            \
                av[M], bv[n_], acc[M][n_], 0, 0, 0);                         \
        _Pragma("unroll")                                                    \
        for (int n_ = 0; n_ < 4; ++n_)                                       \
            acc[M + 1][n_] = __builtin_amdgcn_mfma_f32_16x16x32_bf16(        \
                av[M + 1], bv[n_], acc[M + 1][n_], 0, 0, 0);                 \
        __builtin_amdgcn_s_setprio(0); } while (0)
#define SBAR() __builtin_amdgcn_sched_barrier(0)

// one tile: compute (avC,bvC); trickle-read next set (avN,bvN) from buf[(t+1)&3]
#define TILE(t, avC, bvC, avN, bvN) do {                                     \
        if ((t) < 130) asm volatile("s_waitcnt vmcnt(4)" ::: "memory");      \
        else           asm volatile("s_waitcnt vmcnt(0)" ::: "memory");      \
        __builtin_amdgcn_s_barrier();                                        \
        SBAR();                                                              \
        const u16* LbN = lds + (((t) + 1) & 3) * 16384;                      \
        bvN[0] = *(const s16x8*)&LbN[bob];                                   \
        bvN[1] = *(const s16x8*)&LbN[bob + 512];                             \
        bvN[2] = *(const s16x8*)&LbN[bob + 1024];                            \
        bvN[3] = *(const s16x8*)&LbN[bob + 1536];                            \
        avN[0] = *(const s16x8*)&LbN[aob];                                   \
        avN[1] = *(const s16x8*)&LbN[aob + 512];                             \
        asm volatile("s_waitcnt lgkmcnt(6)" ::: "memory");                   \
        SBAR();                                                              \
        CL2(avC, bvC, 0);                                                    \
        SBAR();                                                              \
        avN[2] = *(const s16x8*)&LbN[aob + 1024];                            \
        avN[3] = *(const s16x8*)&LbN[aob + 1536];                            \
        SBAR();                                                              \
        CL2(avC, bvC, 2);                                                    \
        SBAR();                                                              \
        avN[4] = *(const s16x8*)&LbN[aob + 2048];                            \
        avN[5] = *(const s16x8*)&LbN[aob + 2560];                            \
        SBAR();                                                              \
        CL2(avC, bvC, 4);                                                    \
        SBAR();                                                              \
        avN[6] = *(const s16x8*)&LbN[aob + 3072];                            \
        avN[7] = *(const s16x8*)&LbN[aob + 3584];                            \
        if ((t) + 3 < 132) STAGE((t) + 3);                                   \
        SBAR();                                                              \
        CL2(avC, bvC, 6); } while (0)

    s16x8 av0[8], bv0[4], av1[8], bv1[4];

    STAGE(0); STAGE(1); STAGE(2);                 // 12 loads in flight
    asm volatile("s_waitcnt vmcnt(8)" ::: "memory");   // tile 0 landed
    __builtin_amdgcn_s_barrier();
    SBAR();
    {   // tile-0 operands (full 12 reads; covered by lgkmcnt(6) in TILE(0))
        const u16* Lb = lds;
#pragma unroll
        for (int m_ = 0; m_ < 8; ++m_) av0[m_] = *(const s16x8*)&Lb[aob + m_ * 512];
#pragma unroll
        for (int n_ = 0; n_ < 4; ++n_) bv0[n_] = *(const s16x8*)&Lb[bob + n_ * 512];
    }

    for (int u = 0; u < 66; ++u) {
        const int tA = 2 * u, tB = 2 * u + 1;
        TILE(tA, av0, bv0, av1, bv1);
        if (tB < 131) {
            TILE(tB, av1, bv1, av0, bv0);
        } else {
            asm volatile("s_waitcnt lgkmcnt(0)" ::: "memory");
            SBAR();
            CL2(av1, bv1, 0); CL2(av1, bv1, 2);
            CL2(av1, bv1, 4); CL2(av1, bv1, 6);
        }
    }
#undef STAGE
#undef CL2
#undef SBAR
#undef TILE

#pragma unroll
    for (int n = 0; n < 4; ++n) {
        long col = n0 + wc * 64 + n * 16 + cl;
        float bvv = bias[col];
#pragma unroll
        for (int m = 0; m < 8; ++m) {
            long row = m0 + wr * 128 + m * 16 + kh * 4;
#pragma unroll
            for (int r = 0; r < 4; ++r)
                out[(row + r) * (long)D_OUT + col] = acc[m][n][r] + bvv;
        }
    }
}

// ---------------------------------------------------------------------------
extern "C" void kernel_launch(void* const* d_in, const int* in_sizes, int n_in,
                              void* d_out, int out_size, void* d_ws, size_t ws_size,
                              hipStream_t stream) {
    const float* x  = (const float*)d_in[0];
    const float* bw = (const float*)d_in[1];
    const float* bb = (const float*)d_in[2];
    const float* lA = (const float*)d_in[3];
    const float* lB = (const float*)d_in[4];
    const float* rw = (const float*)d_in[5];
    const float* sc = (const float*)d_in[6];
    float* out = (float*)d_out;

    char* ws = (char*)d_ws;
    u16* Xaug  = (u16*)ws;                      // 8192*4224*2 = 69,206,016 B
    u16* Waug  = (u16*)(ws + 69206016);         // 4096*4224*2 = 34,603,008 B
    u16* A16   = (u16*)(ws + 103809024);        // 128*4096*2  =  1,048,576 B
    float* gates = (float*)(ws + 104857600);    // 8192*8*4    =    262,144 B

    xconv_router_kernel<<<2048, 256, 0, stream>>>(x, rw, sc, Xaug, gates);
    convert_rest_kernel<<<8704, 256, 0, stream>>>(bw, lA, lB, Waug, A16);
    lora_h_kernel<<<256, 256, 0, stream>>>(Xaug, A16, gates);
    main_gemm<<<512, 512, 0, stream>>>(Xaug, Waug, bb, out);
}